// Round 6
// baseline (163.112 us; speedup 1.0000x reference)
//
#include <hip/hip_runtime.h>

// out[(j*f + c)*m + q] = yd[idx[q*K + j]*f + c]
// m=8192, f=512, K=8, fp32. Memory-bound gather+transpose.
//
// Round 6 = Round 5 resubmit (round 5 was an infra failure, never ran).
//  tile = (j, CT=32 cols, QT=128 rows), 256 threads, LDS 17.4KB -> 8 blk/CU.
//  stage: 4x float4 gather loads/thread (one full 128B line per row),
//         transposed scatter into lds[CT][QPAD] (QPAD=132 floats = 528B,
//         16B-aligned rows -> write phase can ds_read_b128).
//  write: 4x ds_read_b128 + 4x nontemporal global_store_dwordx4 per thread;
//         per (j,c) segment = 512B contiguous, full lines, 16B/lane.

#define QT 128
#define CT 32
#define QPAD 132
#define THREADS 256

typedef float f32x4 __attribute__((ext_vector_type(4)));

__global__ __launch_bounds__(THREADS, 4) void gather_transpose_kernel(
    const float* __restrict__ yd, const int* __restrict__ idx,
    float* __restrict__ out, int m, int f, int k)
{
    const int qb = blockIdx.x * QT;
    const int cb = blockIdx.y * CT;
    const int j  = blockIdx.z;
    const int t  = threadIdx.x;

    __shared__ int rows[QT];
    __shared__ float lds[CT][QPAD];

    if (t < QT) rows[t] = idx[(size_t)(qb + t) * k + j];
    __syncthreads();

    // Stage: QT rows x CT floats = 1024 float4s; 4 per thread.
    // row = gid/8, ch = gid%8 -> 8 lanes broadcast-read rows[row] (free).
    #pragma unroll
    for (int it = 0; it < (QT * CT / 4) / THREADS; ++it) {
        const int gid = it * THREADS + t;
        const int row = gid >> 3;
        const int ch  = gid & 7;
        const f32x4 v = *reinterpret_cast<const f32x4*>(
            yd + (size_t)rows[row] * f + cb + (ch << 2));
        const int c0 = ch << 2;
        lds[c0 + 0][row] = v.x;
        lds[c0 + 1][row] = v.y;
        lds[c0 + 2][row] = v.z;
        lds[c0 + 3][row] = v.w;
    }
    __syncthreads();

    // Write: c = gid/32, q4 = gid%32. ds_read_b128 (aligned, stride 528B),
    // float4 nontemporal store; lanes contiguous in q.
    const size_t outb = (size_t)j * f * m + (size_t)cb * m + qb;
    #pragma unroll
    for (int it = 0; it < (QT * CT / 4) / THREADS; ++it) {
        const int gid = it * THREADS + t;
        const int c  = gid >> 5;
        const int q4 = gid & 31;
        const f32x4 v = *reinterpret_cast<const f32x4*>(&lds[c][q4 << 2]);
        __builtin_nontemporal_store(v, reinterpret_cast<f32x4*>(
            out + outb + (size_t)c * m + (q4 << 2)));
    }
}

extern "C" void kernel_launch(void* const* d_in, const int* in_sizes, int n_in,
                              void* d_out, int out_size, void* d_ws, size_t ws_size,
                              hipStream_t stream) {
    // inputs: y_patch (m,64) f32 [only m used], yd_patch (m,f) f32,
    //         idx_k (1,m,K) staged as int32 (absmax 0 in R2/R3 confirms)
    const float* yd = (const float*)d_in[1];
    const int* idx = (const int*)d_in[2];
    float* out = (float*)d_out;

    const int m = in_sizes[0] / 64;
    const int f = in_sizes[1] / m;
    const int k = in_sizes[2] / m;

    dim3 grid(m / QT, f / CT, k);
    hipLaunchKernelGGL(gather_transpose_kernel, grid, dim3(THREADS), 0,
                       stream, yd, idx, out, m, f, k);
}